// Round 6
// baseline (2459.508 us; speedup 1.0000x reference)
//
#include <hip/hip_runtime.h>
#include <cmath>

#define B_ 4
#define T_ 4096
#define D_ 1024

typedef __attribute__((ext_vector_type(4))) float f32x4;
typedef __attribute__((ext_vector_type(2))) float f32x2;
typedef __attribute__((ext_vector_type(8))) short s16x8;

__device__ __forceinline__ f32x4 mfma_bf16(s16x8 a, s16x8 b, f32x4 c) {
    return __builtin_amdgcn_mfma_f32_16x16x32_bf16(a, b, c, 0, 0, 0);
}
__device__ __forceinline__ unsigned short f2bf(float f) {
    union { float f; unsigned int u; } v; v.f = f;
    unsigned int r = v.u + 0x7FFFu + ((v.u >> 16) & 1u);
    return (unsigned short)(r >> 16);
}
// DPP lane permute within 16-lane rows (VALU-speed reduction)
template <int CTRL>
__device__ __forceinline__ float dppf(float x) {
    return __int_as_float(
        __builtin_amdgcn_mov_dpp(__float_as_int(x), CTRL, 0xF, 0xF, true));
}
__device__ __forceinline__ float rowmax16(float v) {
    v = fmaxf(v, dppf<0xB1>(v));
    v = fmaxf(v, dppf<0x4E>(v));
    v = fmaxf(v, dppf<0x141>(v));
    v = fmaxf(v, dppf<0x140>(v));
    return v;
}
__device__ __forceinline__ float rowsum16(float v) {
    v += dppf<0xB1>(v);
    v += dppf<0x4E>(v);
    v += dppf<0x141>(v);
    v += dppf<0x140>(v);
    return v;
}

// ---------------- kernel 1: repack fp32 weights to bf16 w_t[p][h][d][i] ----
__global__ __launch_bounds__(256) void k_wtrans(const float* __restrict__ wq,
                                                const float* __restrict__ wk,
                                                const float* __restrict__ wv,
                                                unsigned short* __restrict__ wt) {
    int p = blockIdx.x >> 4;   // 0..2
    int h = blockIdx.x & 15;
    const float* src = (p == 0) ? wq : (p == 1) ? wk : wv;
    unsigned short* dst = wt + (size_t)((p * 16 + h) * 64) * 64;
    for (int idx = threadIdx.x; idx < 64 * 64; idx += 256) {
        int d = idx >> 6, i = idx & 63;
        dst[d * 64 + i] = f2bf(src[i * 1024 + d * 16 + h]);   // w[i][d][h]
    }
}

// ---------------- kernel 2: QKV projection + fused RoPE ---------------------
// (unchanged from round 4)
__global__ __launch_bounds__(256, 3) void k_qkv(const float* __restrict__ x,
                                             const unsigned short* __restrict__ wt,
                                             unsigned short* __restrict__ Qt,
                                             unsigned short* __restrict__ Kt,
                                             unsigned short* __restrict__ Vt) {
    int bid = blockIdx.x;
    int hp  = bid >> 8;          // head pair 0..7
    int b   = (bid >> 6) & 3;
    int tc  = bid & 63;          // token chunk (64 tokens)
    int t0  = tc * 64;
    int tid = threadIdx.x, w = tid >> 6, lane = tid & 63;
    int quad = lane >> 4, l16 = lane & 15;

    __shared__ alignas(16) unsigned short xh[2 * 64 * 72];   // [hh][t][i], pad 72
    __shared__ alignas(16) unsigned short outl[64 * 68];     // staging tile, pad 68

    for (int n = tid; n < 4096; n += 256) {
        int t = n >> 6, i = n & 63;
        f32x2 v = *(const f32x2*)&x[(size_t)(b * T_ + t0 + t) * D_ + i * 16 + 2 * hp];
        xh[t * 72 + i]        = f2bf(v.x);
        xh[4608 + t * 72 + i] = f2bf(v.y);
    }
    __syncthreads();

    s16x8 xf[2][2];
    #pragma unroll
    for (int hh = 0; hh < 2; ++hh)
        #pragma unroll
        for (int kc = 0; kc < 2; ++kc)
            xf[hh][kc] = *(const s16x8*)&xh[hh * 4608 + (16 * w + l16) * 72 + kc * 32 + quad * 8];

    f32x4 acc[3][2][4];
    #pragma unroll
    for (int p = 0; p < 3; ++p)
        #pragma unroll
        for (int hh = 0; hh < 2; ++hh)
            #pragma unroll
            for (int nt = 0; nt < 4; ++nt)
                acc[p][hh][nt] = (f32x4){0.f, 0.f, 0.f, 0.f};

    #pragma unroll
    for (int p = 0; p < 3; ++p)
        #pragma unroll
        for (int hh = 0; hh < 2; ++hh)
            #pragma unroll
            for (int nt = 0; nt < 4; ++nt)
                #pragma unroll
                for (int kc = 0; kc < 2; ++kc) {
                    const s16x8 wf = *(const s16x8*)&wt[
                        (size_t)((p * 16 + 2 * hp + hh) * 64 + nt * 16 + l16) * 64 + kc * 32 + quad * 8];
                    if (p < 2)
                        acc[p][hh][nt] = mfma_bf16(xf[hh][kc], wf, acc[p][hh][nt]);
                    else
                        acc[p][hh][nt] = mfma_bf16(wf, xf[hh][kc], acc[p][hh][nt]);
                }

    #pragma unroll
    for (int nt = 0; nt < 4; ++nt) {
        int d = nt * 16 + l16;
        float f = exp2f((float)(d * 8 + hp) * -0.02595256324130751f); // -log2(1e4)/512
        #pragma unroll
        for (int r = 0; r < 4; ++r) {
            float ang = (float)(t0 + 16 * w + quad * 4 + r) * f;
            float s, c;
            sincosf(ang, &s, &c);
            float a0 = acc[0][0][nt][r], a1 = acc[0][1][nt][r];
            acc[0][0][nt][r] = a0 * c - a1 * s;
            acc[0][1][nt][r] = a0 * s + a1 * c;
            float k0 = acc[1][0][nt][r], k1 = acc[1][1][nt][r];
            acc[1][0][nt][r] = k0 * c - k1 * s;
            acc[1][1][nt][r] = k0 * s + k1 * c;
        }
    }

    #pragma unroll
    for (int p = 0; p < 3; ++p)
        #pragma unroll
        for (int hh = 0; hh < 2; ++hh) {
            __syncthreads();
            if (p < 2) {
                #pragma unroll
                for (int nt = 0; nt < 4; ++nt)
                    #pragma unroll
                    for (int r = 0; r < 4; ++r)
                        outl[(16 * w + quad * 4 + r) * 68 + nt * 16 + l16] = f2bf(acc[p][hh][nt][r]);
            } else {
                #pragma unroll
                for (int mt = 0; mt < 4; ++mt)
                    #pragma unroll
                    for (int r = 0; r < 4; ++r)
                        outl[(mt * 16 + quad * 4 + r) * 68 + 16 * w + l16] = f2bf(acc[p][hh][mt][r]);
            }
            __syncthreads();
            int h = 2 * hp + hh;
            if (p < 2) {
                unsigned short* g = (p == 0 ? Qt : Kt) + ((size_t)(b * 16 + h) * T_ + t0) * 64;
                for (int n = 2 * tid; n < 4096; n += 512) {
                    int t = n >> 6, dd = n & 63;
                    *(unsigned int*)(g + n) = *(const unsigned int*)&outl[t * 68 + dd];
                }
            } else {
                // tile-blocked V: [h][tile(128)][d64][t&31], tile = t>>5
                unsigned short* g = Vt + (size_t)(b * 16 + h) * 64 * T_;
                for (int n = 2 * tid; n < 4096; n += 512) {
                    int d = n >> 6, tt = n & 63;
                    int tile = 2 * tc + (tt >> 5);
                    *(unsigned int*)(g + (size_t)tile * 2048 + d * 32 + (tt & 31)) =
                        *(const unsigned int*)&outl[d * 68 + tt];
                }
            }
        }
}

// ---------------- kernel 3: flash attention, phase-staggered (32-key) -------
// 1024 thr (16 waves), 1 block/CU (grid 256). Two 8-wave groups on the SAME
// 32-row q-tile split the key stream by 32-key-tile parity (A: even, B: odd).
// Each group keeps its own (m,l,Y); per-q-tile LDS merge combines (online
// softmax is associative). Groups run one interval apart: every barrier
// interval = {one group's softmax: VALU/trans/LDS} || {other group's
// PV + QK^T-next: 32 MFMA + 12 global loads} — both pipes busy by
// construction. LDS kept at ~80 KB (round-4-proven range; round-5's 149 KB
// version killed the container — suspected launch-time LDS overflow).
__global__ __launch_bounds__(1024, 4) void k_attn(const unsigned short* __restrict__ Qt,
                                                  const unsigned short* __restrict__ Kt,
                                                  const unsigned short* __restrict__ Vt,
                                                  float* __restrict__ out) {
    int bid = blockIdx.x;
    int b = (bid >> 1) & 3;                       // batch <- XCD pair
    int j = ((bid >> 3) << 1) | (bid & 1);        // 0..63
    int tid = threadIdx.x;
    int g = tid >> 9;                             // group 0 (A) / 1 (B)
    int gtid = tid & 511;
    int w = gtid >> 6;                            // wave-in-group 0..7
    int quad = (tid >> 4) & 3, l16 = tid & 15;
    int rq = gtid >> 4;                           // softmax row 0..31
    int kk = l16 * 2;                             // 2 keys per lane

    __shared__ alignas(16) float S_red[2][8][32][36];        // per-group S^T partials
    __shared__ alignas(16) unsigned short P_lds[2][32][40];  // per-group P bf16
    __shared__ float alpha_s[2][32];
    __shared__ float m_pub[2][32], l_pub[2][32];

    const float gamma = 0.03125f;   // 1/sqrt(1024)

    #pragma unroll 1
    for (int pass = 0; pass < 2; ++pass) {
        int qt = pass ? j : 127 - j;              // heavy tile first
        int q0 = qt * 32;
        int nkt = qt + 1;                         // 32-key tiles in scan
        int nsA = (nkt + 1) >> 1, nsB = nkt >> 1;
        int ns = g ? nsB : nsA;                   // my group's tile count
        int nIv = (2 * nsA > 2 * nsB + 1) ? 2 * nsA : 2 * nsB + 1;

        // Q fragments (loop-invariant within pass)
        s16x8 qf[2][4];
        #pragma unroll
        for (int qs = 0; qs < 2; ++qs)
            #pragma unroll
            for (int c = 0; c < 4; ++c) {
                int dg = w * 128 + c * 32 + quad * 8;
                int head = dg >> 6, d64 = dg & 63;
                qf[qs][c] = *(const s16x8*)&Qt[((size_t)(b * 16 + head) * T_ + q0 + qs * 16 + l16) * 64 + d64];
            }

        f32x4 Y[8][2];
        #pragma unroll
        for (int mt = 0; mt < 8; ++mt) { Y[mt][0] = (f32x4){0,0,0,0}; Y[mt][1] = (f32x4){0,0,0,0}; }
        float m_reg = -INFINITY, l_reg = 0.f;

        // prologue: S(my first tile tk=g) — group B skips if it has no tiles
        if (ns > 0) {
            #pragma unroll
            for (int kps = 0; kps < 2; ++kps) {
                f32x4 S0 = (f32x4){0,0,0,0}, S1 = (f32x4){0,0,0,0};
                #pragma unroll
                for (int c = 0; c < 4; ++c) {
                    int dg = w * 128 + c * 32 + quad * 8;
                    int head = dg >> 6, d64 = dg & 63;
                    s16x8 kf = *(const s16x8*)&Kt[((size_t)(b * 16 + head) * T_ + g * 32 + kps * 16 + l16) * 64 + d64];
                    S0 = mfma_bf16(kf, qf[0][c], S0);
                    S1 = mfma_bf16(kf, qf[1][c], S1);
                }
                *(f32x4*)&S_red[g][w][l16][kps * 16 + quad * 4] = S0;
                *(f32x4*)&S_red[g][w][16 + l16][kps * 16 + quad * 4] = S1;
            }
        }
        __syncthreads();

        s16x8 vfA[4];   // V d-frags mt 0..3, prefetched in my softmax step
        s16x8 vfB[4];   // V d-frags mt 4..7, issued at my MFMA-step start

        for (int iv = 0; iv < nIv; ++iv) {
            int ph = iv - g;
            int s = ph >> 1;
            bool act = (ph >= 0) && (s < ns);
            if (act && !(ph & 1)) {
                // ---- softmax step, my tile s (tk = 2s+g) ----
                int tk = 2 * s + g;
                #pragma unroll
                for (int mt = 0; mt < 4; ++mt) {
                    int dg = w * 128 + mt * 16 + l16;
                    int head = dg >> 6, d64 = dg & 63;
                    vfA[mt] = *(const s16x8*)&Vt[
                        (((size_t)(b * 16 + head) * 128 + tk) * 64 + d64) * 32 + quad * 8];
                }
                float s0 = 0.f, s1 = 0.f;
                #pragma unroll
                for (int sl = 0; sl < 8; ++sl) {
                    f32x2 v = *(const f32x2*)&S_red[g][sl][rq][kk];
                    s0 += v.x; s1 += v.y;
                }
                int qg = q0 + rq;
                int kb = tk * 32 + kk;
                s0 = (kb     > qg) ? -INFINITY : s0 * gamma;
                s1 = (kb + 1 > qg) ? -INFINITY : s1 * gamma;
                float mx = rowmax16(fmaxf(s0, s1));
                float m_new = fmaxf(m_reg, mx);
                float alpha = __expf(m_reg - m_new);
                float p0 = __expf(s0 - m_new), p1 = __expf(s1 - m_new);
                float ps = rowsum16(p0 + p1);
                l_reg = alpha * l_reg + ps;
                m_reg = m_new;
                if ((tid & 15) == 0) alpha_s[g][rq] = alpha;
                unsigned int pp = (unsigned int)f2bf(p0) | ((unsigned int)f2bf(p1) << 16);
                *(unsigned int*)&P_lds[g][rq][kk] = pp;
            } else if (act) {
                // ---- MFMA step, my tile s (tk = 2s+g) ----
                int tk = 2 * s + g;
                #pragma unroll
                for (int mt = 0; mt < 4; ++mt) {
                    int dg = w * 128 + (mt + 4) * 16 + l16;
                    int head = dg >> 6, d64 = dg & 63;
                    vfB[mt] = *(const s16x8*)&Vt[
                        (((size_t)(b * 16 + head) * 128 + tk) * 64 + d64) * 32 + quad * 8];
                }
                float a0 = alpha_s[g][l16], a1 = alpha_s[g][16 + l16];
                s16x8 pf0 = *(const s16x8*)&P_lds[g][l16][quad * 8];
                s16x8 pf1 = *(const s16x8*)&P_lds[g][16 + l16][quad * 8];
                int scale = __any((a0 < 1.f) || (a1 < 1.f));
                __builtin_amdgcn_s_setprio(1);
                if (scale) {
                    #pragma unroll
                    for (int mt = 0; mt < 8; ++mt) { Y[mt][0] *= a0; Y[mt][1] *= a1; }
                }
                // PV mt 0..3 (vfA prefetched last interval: latency covered)
                #pragma unroll
                for (int mt = 0; mt < 4; ++mt) {
                    Y[mt][0] = mfma_bf16(vfA[mt], pf0, Y[mt][0]);
                    Y[mt][1] = mfma_bf16(vfA[mt], pf1, Y[mt][1]);
                }
                // S(next tile tk+2): inline K loads + 16 MFMA — also covers
                // vfB load latency before PV mt 4..7 consumes it
                if (s + 1 < ns) {
                    int kb2 = (tk + 2) * 32;
                    #pragma unroll
                    for (int kps = 0; kps < 2; ++kps) {
                        f32x4 S0 = (f32x4){0,0,0,0}, S1 = (f32x4){0,0,0,0};
                        #pragma unroll
                        for (int c = 0; c < 4; ++c) {
                            int dg = w * 128 + c * 32 + quad * 8;
                            int head = dg >> 6, d64 = dg & 63;
                            s16x8 kf = *(const s16x8*)&Kt[
                                ((size_t)(b * 16 + head) * T_ + kb2 + kps * 16 + l16) * 64 + d64];
                            S0 = mfma_bf16(kf, qf[0][c], S0);
                            S1 = mfma_bf16(kf, qf[1][c], S1);
                        }
                        *(f32x4*)&S_red[g][w][l16][kps * 16 + quad * 4] = S0;
                        *(f32x4*)&S_red[g][w][16 + l16][kps * 16 + quad * 4] = S1;
                    }
                }
                // PV mt 4..7
                #pragma unroll
                for (int mt = 0; mt < 4; ++mt) {
                    Y[mt + 4][0] = mfma_bf16(vfB[mt], pf0, Y[mt + 4][0]);
                    Y[mt + 4][1] = mfma_bf16(vfB[mt], pf1, Y[mt + 4][1]);
                }
                __builtin_amdgcn_s_setprio(0);
            }
            __syncthreads();
        }

        // ---- merge groups + store (S_red reused as f32 scratch) ----
        if ((tid & 15) == 0) { m_pub[g][rq] = m_reg; l_pub[g][rq] = l_reg; }
        __syncthreads();
        float* mrg = &S_red[0][0][0][0];    // 18432 floats available; need 16896
        #pragma unroll 1
        for (int ck = 0; ck < 2; ++ck) {
            if (g == 1 && (w >> 2) == ck) {
                #pragma unroll
                for (int mt = 0; mt < 8; ++mt)
                    #pragma unroll
                    for (int qs = 0; qs < 2; ++qs)
                        #pragma unroll
                        for (int r = 0; r < 4; ++r)
                            mrg[((w & 3) * 32 + qs * 16 + l16) * 132 + mt * 16 + quad * 4 + r] = Y[mt][qs][r];
            }
            __syncthreads();
            if (g == 0 && (w >> 2) == ck) {
                #pragma unroll
                for (int qs = 0; qs < 2; ++qs) {
                    int q = qs * 16 + l16;
                    float mA = m_pub[0][q], mB = m_pub[1][q];
                    float m = fmaxf(mA, mB);
                    float sA = __expf(mA - m);
                    float sB = (mB == -INFINITY) ? 0.f : __expf(mB - m);
                    float linv = 1.f / (sA * l_pub[0][q] + sB * l_pub[1][q]);
                    #pragma unroll
                    for (int mt = 0; mt < 8; ++mt)
                        #pragma unroll
                        for (int r = 0; r < 4; ++r) {
                            float yb = mrg[((w & 3) * 32 + q) * 132 + mt * 16 + quad * 4 + r];
                            float y = (sA * Y[mt][qs][r] + sB * yb) * linv;
                            int dg = w * 128 + mt * 16 + quad * 4 + r;
                            int head = dg >> 6, d64 = dg & 63;
                            int e = d64 * 16 + head;
                            out[(size_t)(b * T_ + q0 + q) * D_ + e] = y;
                        }
                }
            }
            __syncthreads();
        }
    }
}

extern "C" void kernel_launch(void* const* d_in, const int* in_sizes, int n_in,
                              void* d_out, int out_size, void* d_ws, size_t ws_size,
                              hipStream_t stream) {
    const float* x  = (const float*)d_in[0];
    const float* wq = (const float*)d_in[1];
    const float* wk = (const float*)d_in[2];
    const float* wv = (const float*)d_in[3];
    unsigned short* ws = (unsigned short*)d_ws;

    const size_t WT_ELEMS  = 3 * 16 * 64 * 64;          // 196608
    const size_t QKV_ELEMS = (size_t)B_ * 16 * T_ * 64; // 16777216 each
    const size_t NEED_BYTES = (WT_ELEMS + 3 * QKV_ELEMS) * sizeof(unsigned short);
    if (ws_size < NEED_BYTES) return;

    unsigned short* wt = ws;
    unsigned short* Qt = ws + WT_ELEMS;
    unsigned short* Kt = Qt + QKV_ELEMS;
    unsigned short* Vt = Kt + QKV_ELEMS;
    float* outp = (float*)d_out;

    k_wtrans<<<48, 256, 0, stream>>>(wq, wk, wv, wt);
    k_qkv<<<2048, 256, 0, stream>>>(x, wt, Qt, Kt, Vt);
    k_attn<<<256, 1024, 0, stream>>>(Qt, Kt, Vt, outp);
}

// Round 8
// 704.127 us; speedup vs baseline: 3.4930x; 3.4930x over previous
//
#include <hip/hip_runtime.h>
#include <cmath>

#define B_ 4
#define T_ 4096
#define D_ 1024

typedef __attribute__((ext_vector_type(4))) float f32x4;
typedef __attribute__((ext_vector_type(2))) float f32x2;
typedef __attribute__((ext_vector_type(8))) short s16x8;

__device__ __forceinline__ f32x4 mfma_bf16(s16x8 a, s16x8 b, f32x4 c) {
    return __builtin_amdgcn_mfma_f32_16x16x32_bf16(a, b, c, 0, 0, 0);
}
__device__ __forceinline__ unsigned short f2bf(float f) {
    union { float f; unsigned int u; } v; v.f = f;
    unsigned int r = v.u + 0x7FFFu + ((v.u >> 16) & 1u);
    return (unsigned short)(r >> 16);
}
// DPP lane permute within 16-lane rows (VALU-speed reduction)
template <int CTRL>
__device__ __forceinline__ float dppf(float x) {
    return __int_as_float(
        __builtin_amdgcn_mov_dpp(__float_as_int(x), CTRL, 0xF, 0xF, true));
}
__device__ __forceinline__ float rowmax16(float v) {
    v = fmaxf(v, dppf<0xB1>(v));
    v = fmaxf(v, dppf<0x4E>(v));
    v = fmaxf(v, dppf<0x141>(v));
    v = fmaxf(v, dppf<0x140>(v));
    return v;
}
__device__ __forceinline__ float rowsum16(float v) {
    v += dppf<0xB1>(v);
    v += dppf<0x4E>(v);
    v += dppf<0x141>(v);
    v += dppf<0x140>(v);
    return v;
}

// ---------------- kernel 1: repack fp32 weights to bf16 w_t[p][h][d][i] ----
__global__ __launch_bounds__(256) void k_wtrans(const float* __restrict__ wq,
                                                const float* __restrict__ wk,
                                                const float* __restrict__ wv,
                                                unsigned short* __restrict__ wt) {
    int p = blockIdx.x >> 4;   // 0..2
    int h = blockIdx.x & 15;
    const float* src = (p == 0) ? wq : (p == 1) ? wk : wv;
    unsigned short* dst = wt + (size_t)((p * 16 + h) * 64) * 64;
    for (int idx = threadIdx.x; idx < 64 * 64; idx += 256) {
        int d = idx >> 6, i = idx & 63;
        dst[d * 64 + i] = f2bf(src[i * 1024 + d * 16 + h]);   // w[i][d][h]
    }
}

// ---------------- kernel 2: QKV projection + fused RoPE ---------------------
// R4-proven structure; only change: libm sincosf -> __sincosf (HW v_sin/v_cos,
// ~4e-4 rad arg-reduction error << bf16 output precision 2^-8). k_qkv is
// VALU-bound on trig (memory ideal is ~25us), so this is the lever here.
__global__ __launch_bounds__(256, 3) void k_qkv(const float* __restrict__ x,
                                             const unsigned short* __restrict__ wt,
                                             unsigned short* __restrict__ Qt,
                                             unsigned short* __restrict__ Kt,
                                             unsigned short* __restrict__ Vt) {
    int bid = blockIdx.x;
    int hp  = bid >> 8;          // head pair 0..7
    int b   = (bid >> 6) & 3;
    int tc  = bid & 63;          // token chunk (64 tokens)
    int t0  = tc * 64;
    int tid = threadIdx.x, w = tid >> 6, lane = tid & 63;
    int quad = lane >> 4, l16 = lane & 15;

    __shared__ alignas(16) unsigned short xh[2 * 64 * 72];   // [hh][t][i], pad 72
    __shared__ alignas(16) unsigned short outl[64 * 68];     // staging tile, pad 68

    for (int n = tid; n < 4096; n += 256) {
        int t = n >> 6, i = n & 63;
        f32x2 v = *(const f32x2*)&x[(size_t)(b * T_ + t0 + t) * D_ + i * 16 + 2 * hp];
        xh[t * 72 + i]        = f2bf(v.x);
        xh[4608 + t * 72 + i] = f2bf(v.y);
    }
    __syncthreads();

    s16x8 xf[2][2];
    #pragma unroll
    for (int hh = 0; hh < 2; ++hh)
        #pragma unroll
        for (int kc = 0; kc < 2; ++kc)
            xf[hh][kc] = *(const s16x8*)&xh[hh * 4608 + (16 * w + l16) * 72 + kc * 32 + quad * 8];

    f32x4 acc[3][2][4];
    #pragma unroll
    for (int p = 0; p < 3; ++p)
        #pragma unroll
        for (int hh = 0; hh < 2; ++hh)
            #pragma unroll
            for (int nt = 0; nt < 4; ++nt)
                acc[p][hh][nt] = (f32x4){0.f, 0.f, 0.f, 0.f};

    #pragma unroll
    for (int p = 0; p < 3; ++p)
        #pragma unroll
        for (int hh = 0; hh < 2; ++hh)
            #pragma unroll
            for (int nt = 0; nt < 4; ++nt)
                #pragma unroll
                for (int kc = 0; kc < 2; ++kc) {
                    const s16x8 wf = *(const s16x8*)&wt[
                        (size_t)((p * 16 + 2 * hp + hh) * 64 + nt * 16 + l16) * 64 + kc * 32 + quad * 8];
                    if (p < 2)
                        acc[p][hh][nt] = mfma_bf16(xf[hh][kc], wf, acc[p][hh][nt]);
                    else
                        acc[p][hh][nt] = mfma_bf16(wf, xf[hh][kc], acc[p][hh][nt]);
                }

    #pragma unroll
    for (int nt = 0; nt < 4; ++nt) {
        int d = nt * 16 + l16;
        float f = exp2f((float)(d * 8 + hp) * -0.02595256324130751f); // -log2(1e4)/512
        #pragma unroll
        for (int r = 0; r < 4; ++r) {
            float ang = (float)(t0 + 16 * w + quad * 4 + r) * f;
            float s, c;
            __sincosf(ang, &s, &c);
            float a0 = acc[0][0][nt][r], a1 = acc[0][1][nt][r];
            acc[0][0][nt][r] = a0 * c - a1 * s;
            acc[0][1][nt][r] = a0 * s + a1 * c;
            float k0 = acc[1][0][nt][r], k1 = acc[1][1][nt][r];
            acc[1][0][nt][r] = k0 * c - k1 * s;
            acc[1][1][nt][r] = k0 * s + k1 * c;
        }
    }

    #pragma unroll
    for (int p = 0; p < 3; ++p)
        #pragma unroll
        for (int hh = 0; hh < 2; ++hh) {
            __syncthreads();
            if (p < 2) {
                #pragma unroll
                for (int nt = 0; nt < 4; ++nt)
                    #pragma unroll
                    for (int r = 0; r < 4; ++r)
                        outl[(16 * w + quad * 4 + r) * 68 + nt * 16 + l16] = f2bf(acc[p][hh][nt][r]);
            } else {
                #pragma unroll
                for (int mt = 0; mt < 4; ++mt)
                    #pragma unroll
                    for (int r = 0; r < 4; ++r)
                        outl[(mt * 16 + quad * 4 + r) * 68 + 16 * w + l16] = f2bf(acc[p][hh][mt][r]);
            }
            __syncthreads();
            int h = 2 * hp + hh;
            if (p < 2) {
                unsigned short* g = (p == 0 ? Qt : Kt) + ((size_t)(b * 16 + h) * T_ + t0) * 64;
                for (int n = 2 * tid; n < 4096; n += 512) {
                    int t = n >> 6, dd = n & 63;
                    *(unsigned int*)(g + n) = *(const unsigned int*)&outl[t * 68 + dd];
                }
            } else {
                // tile-blocked V: [h][tile(128)][d64][t&31], tile = t>>5
                unsigned short* g = Vt + (size_t)(b * 16 + h) * 64 * T_;
                for (int n = 2 * tid; n < 4096; n += 512) {
                    int d = n >> 6, tt = n & 63;
                    int tile = 2 * tc + (tt >> 5);
                    *(unsigned int*)(g + (size_t)tile * 2048 + d * 32 + (tt & 31)) =
                        *(const unsigned int*)&outl[d * 68 + tt];
                }
            }
        }
}

// ---------------- kernel 3: flash attention, KVBLK=64 (R4-proven) ----------
// NOTE (R7 lesson): the reference's scores einsum contracts over the FULL
// d=1024 (one attention map shared by all heads; gamma=1/32). The 8-wave
// d-sliced partial-S + S_red cross-wave reduce is therefore STRUCTURAL —
// per-wave d-slice 128 is forced by the Y-register budget (d_slice*32q/64
// lanes = 64 VGPRs), and S_red (1 KB LDS per key) beats Q-in-LDS key-sliced
// alternatives (4 KB per key). Only change vs R4: defer-max (THR=8) so the
// rescale-skip branch fires on most tiles (P <= e^8, safe in bf16/f32).
__global__ __launch_bounds__(512, 2) void k_attn(const unsigned short* __restrict__ Qt,
                                              const unsigned short* __restrict__ Kt,
                                              const unsigned short* __restrict__ Vt,
                                              float* __restrict__ out) {
    int bid = blockIdx.x;
    int b = (bid >> 1) & 3;                      // batch <- XCD pair (R3 win)
    int q = ((bid >> 3) & 31) * 2 + (bid & 1);   // 0..63
    int qt = (bid < 256) ? (127 - q) : q;        // heavy blocks first
    int q0 = qt * 32;
    int tid = threadIdx.x, w = tid >> 6, lane = tid & 63;
    int quad = lane >> 4, l16 = lane & 15;

    __shared__ alignas(16) float S_red[8][32][68];          // partial S^T, 64 keys, pad 68
    __shared__ alignas(16) unsigned short P_lds[32][72];    // P[q][kpos] bf16, pad 72
    __shared__ float alpha_s[32], l_st[32];

    // Q fragments (loop-invariant): B-operand, [q][d] d-contig
    s16x8 qf[2][4];
    #pragma unroll
    for (int qs = 0; qs < 2; ++qs)
        #pragma unroll
        for (int c = 0; c < 4; ++c) {
            int dg = w * 128 + c * 32 + quad * 8;
            int head = dg >> 6, d64 = dg & 63;
            qf[qs][c] = *(const s16x8*)&Qt[((size_t)(b * 16 + head) * T_ + q0 + qs * 16 + l16) * 64 + d64];
        }

    f32x4 Y[8][2];
    #pragma unroll
    for (int mt = 0; mt < 8; ++mt) { Y[mt][0] = (f32x4){0,0,0,0}; Y[mt][1] = (f32x4){0,0,0,0}; }

    const float gamma = 0.03125f;   // 1/sqrt(1024)
    int rq = tid >> 4;              // softmax row 0..31 (16 lanes per row)
    int kk4 = (tid & 15) * 4;       // 4 keys per thread
    int nkt = (qt >> 1) + 1;        // 64-key tiles
    float m_reg = -INFINITY, l_reg = 0.f;   // row-replicated (DPP keeps uniform)

    // ---- prologue: S(tile 0) = keys 0..63 into S_red ----
    {
        f32x4 S[4][2];
        #pragma unroll
        for (int kps = 0; kps < 4; ++kps) { S[kps][0] = (f32x4){0,0,0,0}; S[kps][1] = (f32x4){0,0,0,0}; }
        #pragma unroll
        for (int kps = 0; kps < 4; ++kps)
            #pragma unroll
            for (int c = 0; c < 4; ++c) {
                int dg = w * 128 + c * 32 + quad * 8;
                int head = dg >> 6, d64 = dg & 63;
                s16x8 kf = *(const s16x8*)&Kt[((size_t)(b * 16 + head) * T_ + kps * 16 + l16) * 64 + d64];
                S[kps][0] = mfma_bf16(kf, qf[0][c], S[kps][0]);
                S[kps][1] = mfma_bf16(kf, qf[1][c], S[kps][1]);
            }
        #pragma unroll
        for (int kps = 0; kps < 4; ++kps)
            #pragma unroll
            for (int qs = 0; qs < 2; ++qs)
                *(f32x4*)&S_red[w][qs * 16 + l16][kps * 16 + quad * 4] = S[kps][qs];
    }
    __syncthreads();

    s16x8 vfA[8];   // V keys [kbase, kbase+32), prefetched in phase A
    s16x8 vfB[8];   // V keys [kbase+32, kbase+64), loaded at phase-B start

    for (int kt = 0; kt < nkt; ++kt) {
        int kbase = kt * 64;
        bool more = (kt + 1 < nkt);

        // ---- phase A: prefetch V half-A, then softmax(64 keys) ----
        #pragma unroll
        for (int mt = 0; mt < 8; ++mt) {
            int dg = w * 128 + mt * 16 + l16;
            int head = dg >> 6, d64 = dg & 63;
            vfA[mt] = *(const s16x8*)&Vt[
                (((size_t)(b * 16 + head) * 128 + 2 * kt) * 64 + d64) * 32 + quad * 8];
        }

        f32x4 s = {0.f, 0.f, 0.f, 0.f};
        #pragma unroll
        for (int sl = 0; sl < 8; ++sl) {
            f32x4 v = *(const f32x4*)&S_red[sl][rq][kk4];
            s.x += v.x; s.y += v.y; s.z += v.z; s.w += v.w;
        }
        int qg = q0 + rq;
        int kb = kbase + kk4;
        s.x = (kb     > qg) ? -INFINITY : s.x * gamma;
        s.y = (kb + 1 > qg) ? -INFINITY : s.y * gamma;
        s.z = (kb + 2 > qg) ? -INFINITY : s.z * gamma;
        s.w = (kb + 3 > qg) ? -INFINITY : s.w * gamma;
        float mx = rowmax16(fmaxf(fmaxf(s.x, s.y), fmaxf(s.z, s.w)));
        // defer-max (T13, THR=8): keep old m unless it grew by >8 -> alpha==1
        // exactly on most tiles, so the rescale-skip branch below fires.
        float m_new = (mx > m_reg + 8.f) ? mx : m_reg;
        float alpha = __expf(m_reg - m_new);
        float p0 = __expf(s.x - m_new), p1 = __expf(s.y - m_new);
        float p2 = __expf(s.z - m_new), p3 = __expf(s.w - m_new);
        float ps = rowsum16((p0 + p1) + (p2 + p3));
        l_reg = alpha * l_reg + ps;
        m_reg = m_new;
        if ((tid & 15) == 0) alpha_s[rq] = alpha;
        unsigned int plo = (unsigned int)f2bf(p0) | ((unsigned int)f2bf(p1) << 16);
        unsigned int phi = (unsigned int)f2bf(p2) | ((unsigned int)f2bf(p3) << 16);
        *(unsigned long long*)&P_lds[rq][kk4] =
            (unsigned long long)plo | ((unsigned long long)phi << 32);
        __syncthreads();

        // ---- phase B: PV (2 halves) + S(next tile) ----
        // issue V half-B loads first; PV half-A MFMAs cover their latency
        #pragma unroll
        for (int mt = 0; mt < 8; ++mt) {
            int dg = w * 128 + mt * 16 + l16;
            int head = dg >> 6, d64 = dg & 63;
            vfB[mt] = *(const s16x8*)&Vt[
                (((size_t)(b * 16 + head) * 128 + 2 * kt + 1) * 64 + d64) * 32 + quad * 8];
        }
        float a0 = alpha_s[l16], a1 = alpha_s[16 + l16];
        s16x8 pf0a = *(const s16x8*)&P_lds[l16][quad * 8];
        s16x8 pf0b = *(const s16x8*)&P_lds[l16][32 + quad * 8];
        s16x8 pf1a = *(const s16x8*)&P_lds[16 + l16][quad * 8];
        s16x8 pf1b = *(const s16x8*)&P_lds[16 + l16][32 + quad * 8];
        int scale = __any((a0 < 1.f) || (a1 < 1.f));
        __builtin_amdgcn_s_setprio(1);
        if (scale) {
            #pragma unroll
            for (int mt = 0; mt < 8; ++mt) { Y[mt][0] *= a0; Y[mt][1] *= a1; }
        }
        #pragma unroll
        for (int mt = 0; mt < 8; ++mt) {
            Y[mt][0] = mfma_bf16(vfA[mt], pf0a, Y[mt][0]);
            Y[mt][1] = mfma_bf16(vfA[mt], pf1a, Y[mt][1]);
        }
        #pragma unroll
        for (int mt = 0; mt < 8; ++mt) {
            Y[mt][0] = mfma_bf16(vfB[mt], pf0b, Y[mt][0]);
            Y[mt][1] = mfma_bf16(vfB[mt], pf1b, Y[mt][1]);
        }
        if (more) {
            f32x4 S[4][2];
            #pragma unroll
            for (int kps = 0; kps < 4; ++kps) { S[kps][0] = (f32x4){0,0,0,0}; S[kps][1] = (f32x4){0,0,0,0}; }
            #pragma unroll
            for (int kps = 0; kps < 4; ++kps)
                #pragma unroll
                for (int c = 0; c < 4; ++c) {
                    int dg = w * 128 + c * 32 + quad * 8;
                    int head = dg >> 6, d64 = dg & 63;
                    s16x8 kf = *(const s16x8*)&Kt[
                        ((size_t)(b * 16 + head) * T_ + kbase + 64 + kps * 16 + l16) * 64 + d64];
                    S[kps][0] = mfma_bf16(kf, qf[0][c], S[kps][0]);
                    S[kps][1] = mfma_bf16(kf, qf[1][c], S[kps][1]);
                }
            #pragma unroll
            for (int kps = 0; kps < 4; ++kps)
                #pragma unroll
                for (int qs = 0; qs < 2; ++qs)
                    *(f32x4*)&S_red[w][qs * 16 + l16][kps * 16 + quad * 4] = S[kps][qs];
        }
        __builtin_amdgcn_s_setprio(0);
        __syncthreads();
    }

    // ---- epilogue: publish l, normalize, map d->(h,d64)->e, store fp32 ----
    if ((tid & 15) == 0) l_st[rq] = l_reg;
    __syncthreads();
    float inv0 = 1.f / l_st[l16], inv1 = 1.f / l_st[16 + l16];
    #pragma unroll
    for (int mt = 0; mt < 8; ++mt)
        #pragma unroll
        for (int r = 0; r < 4; ++r) {
            int dg = w * 128 + mt * 16 + quad * 4 + r;
            int head = dg >> 6, d64 = dg & 63;
            int e = d64 * 16 + head;
            out[(size_t)(b * T_ + q0 + l16) * D_ + e]      = Y[mt][0][r] * inv0;
            out[(size_t)(b * T_ + q0 + 16 + l16) * D_ + e] = Y[mt][1][r] * inv1;
        }
}

extern "C" void kernel_launch(void* const* d_in, const int* in_sizes, int n_in,
                              void* d_out, int out_size, void* d_ws, size_t ws_size,
                              hipStream_t stream) {
    const float* x  = (const float*)d_in[0];
    const float* wq = (const float*)d_in[1];
    const float* wk = (const float*)d_in[2];
    const float* wv = (const float*)d_in[3];
    unsigned short* ws = (unsigned short*)d_ws;

    const size_t WT_ELEMS  = 3 * 16 * 64 * 64;          // 196608
    const size_t QKV_ELEMS = (size_t)B_ * 16 * T_ * 64; // 16777216 each
    const size_t NEED_BYTES = (WT_ELEMS + 3 * QKV_ELEMS) * sizeof(unsigned short);
    if (ws_size < NEED_BYTES) return;

    unsigned short* wt = ws;
    unsigned short* Qt = ws + WT_ELEMS;
    unsigned short* Kt = Qt + QKV_ELEMS;
    unsigned short* Vt = Kt + QKV_ELEMS;
    float* outp = (float*)d_out;

    k_wtrans<<<48, 256, 0, stream>>>(wq, wk, wv, wt);
    k_qkv<<<2048, 256, 0, stream>>>(x, wt, Qt, Kt, Vt);
    k_attn<<<512, 512, 0, stream>>>(Qt, Kt, Vt, outp);
}